// Round 4
// baseline (89.707 us; speedup 1.0000x reference)
//
#include <hip/hip_runtime.h>
#include <hip/hip_bf16.h>

#define IMG_H 384
#define IMG_W 384
#define KSZ 9
#define KR 4              // k//2
#define TILE 16
#define TIN (TILE + 2*KR) // 24
#define SPX 25            // row stride in float4 units
#define PLANE (IMG_H * IMG_W)
#define REPS 8            // measurement round: 8 redundant passes (identical writes)

__global__ __launch_bounds__(256) void abf_kernel(
    const float* __restrict__ input,   // [2][3][384][384]
    const float* __restrict__ sigmas,  // [2][2][384][384]
    float* __restrict__ out)           // [2][3][384][384]
{
    __shared__ float4 s_in[TIN * SPX];

    const int b      = blockIdx.z & 1;   // batch; blockIdx.z>>1 = replica (redundant work)
    const int tile_x = blockIdx.x * TILE;
    const int tile_y = blockIdx.y * TILE;
    const int tx     = threadIdx.x;   // 0..15
    const int ty     = threadIdx.y;   // 0..15
    const int tid    = ty * TILE + tx;

    // ---- stage 24x24 halo tile, channel-packed (ch0,ch1,ch2,pad) ----
    const float* inb = input + (size_t)b * 3 * PLANE;
    for (int p = tid; p < TIN * TIN; p += 256) {
        int py = p / TIN;
        int px = p - py * TIN;
        int gy = tile_y + py - KR;
        int gx = tile_x + px - KR;
        float4 v = make_float4(0.f, 0.f, 0.f, 0.f);
        if (gy >= 0 && gy < IMG_H && gx >= 0 && gx < IMG_W) {
            int gidx = gy * IMG_W + gx;
            v.x = inb[gidx];
            v.y = inb[PLANE + gidx];
            v.z = inb[2 * PLANE + gidx];
        }
        s_in[py * SPX + px] = v;
    }
    __syncthreads();

    const int ox = tile_x + tx;
    const int oy = tile_y + ty;

    const float* sgb = sigmas + (size_t)b * 2 * PLANE;
    const float sg0 = sgb[oy * IMG_W + ox];
    const float sg1 = sgb[PLANE + oy * IMG_W + ox];
    const float sig_s = 1.0f / (fabsf(sg0) + 1e-12f);
    const float sig_r = 1.0f / (fabsf(sg1) + 1e-12f);
    // w = exp2( sc * A + dsq * B ),  sc = ry^2 + rx^2,  dsq = sum_c (v_c - cen_c)^2
    const float A = -0.5f * 1.44269504f * sig_s * sig_s;
    const float B = -0.5f * 1.44269504f * sig_r * sig_r;

    const float4 cen = s_in[(ty + KR) * SPX + (tx + KR)];

    float wsum = 0.0f, acc0 = 0.0f, acc1 = 0.0f, acc2 = 0.0f;

    // dy rolled (bounded liveness: <=9 float4 live), dx fully unrolled
    #pragma unroll 1
    for (int dy = 0; dy < KSZ; ++dy) {
        const float ry2 = (float)((dy - KR) * (dy - KR));
        const float syA = ry2 * A;
        const float4* __restrict__ row = &s_in[(ty + dy) * SPX + tx];
        #pragma unroll
        for (int dx = 0; dx < KSZ; ++dx) {
            const float rx2 = (float)((dx - KR) * (dx - KR));
            const float4 v = row[dx];
            const float d0 = v.x - cen.x;
            const float d1 = v.y - cen.y;
            const float d2 = v.z - cen.z;
            const float dsq = fmaf(d0, d0, fmaf(d1, d1, d2 * d2));
            const float scA = fmaf(rx2, A, syA);
            const float w = __builtin_amdgcn_exp2f(fmaf(dsq, B, scA));
            wsum += w;
            acc0 = fmaf(w, v.x, acc0);
            acc1 = fmaf(w, v.y, acc1);
            acc2 = fmaf(w, v.z, acc2);
        }
    }

    const float inv = __builtin_amdgcn_rcpf(wsum);  // wsum >= 1 (center tap w == 1)
    float* outb = out + (size_t)b * 3 * PLANE;
    const int oidx = oy * IMG_W + ox;
    outb[oidx]             = acc0 * inv;
    outb[PLANE + oidx]     = acc1 * inv;
    outb[2 * PLANE + oidx] = acc2 * inv;
}

extern "C" void kernel_launch(void* const* d_in, const int* in_sizes, int n_in,
                              void* d_out, int out_size, void* d_ws, size_t ws_size,
                              hipStream_t stream) {
    const float* input  = (const float*)d_in[0];
    const float* sigmas = (const float*)d_in[1];
    float* out = (float*)d_out;

    dim3 block(TILE, TILE, 1);
    dim3 grid(IMG_W / TILE, IMG_H / TILE, 2 * REPS);  // z: batch x replica (identical writes)
    abf_kernel<<<grid, block, 0, stream>>>(input, sigmas, out);
}

// Round 5
// 18.364 us; speedup vs baseline: 4.8848x; 4.8848x over previous
//
#include <hip/hip_runtime.h>
#include <hip/hip_bf16.h>

#define IMG_H 384
#define IMG_W 384
#define KSZ 9
#define KR 4                 // k//2
#define TILE_W 16
#define TILE_H 8
#define TIN_W (TILE_W + 2*KR) // 24
#define TIN_H (TILE_H + 2*KR) // 16
#define SPX 25                // halo row stride in float4 units
#define PLANE (IMG_H * IMG_W)

__global__ __launch_bounds__(256) void abf_kernel(
    const float* __restrict__ input,   // [2][3][384][384]
    const float* __restrict__ sigmas,  // [2][2][384][384]
    float* __restrict__ out)           // [2][3][384][384]
{
    __shared__ float4 s_in[TIN_H * SPX];           // 6.25 KB halo tile (ch-packed)
    __shared__ float4 s_comb[TILE_H * TILE_W];     // 2 KB partial-sum combine

    const int b      = blockIdx.z;
    const int tile_x = blockIdx.x * TILE_W;
    const int tile_y = blockIdx.y * TILE_H;
    const int tx     = threadIdx.x;   // 0..15
    const int ty     = threadIdx.y;   // 0..7
    const int tz     = threadIdx.z;   // 0..1  (wave-uniform: tid = tz*128 + ty*16 + tx)
    const int tid    = tz * 128 + ty * 16 + tx;

    // ---- stage 24x16 halo tile, channel-packed (ch0,ch1,ch2,pad) ----
    const float* inb = input + (size_t)b * 3 * PLANE;
    for (int p = tid; p < TIN_H * TIN_W; p += 256) {
        int py = p / TIN_W;
        int px = p - py * TIN_W;
        int gy = tile_y + py - KR;
        int gx = tile_x + px - KR;
        float4 v = make_float4(0.f, 0.f, 0.f, 0.f);
        if (gy >= 0 && gy < IMG_H && gx >= 0 && gx < IMG_W) {
            int gidx = gy * IMG_W + gx;
            v.x = inb[gidx];
            v.y = inb[PLANE + gidx];
            v.z = inb[2 * PLANE + gidx];
        }
        s_in[py * SPX + px] = v;
    }
    __syncthreads();

    const int ox = tile_x + tx;
    const int oy = tile_y + ty;

    const float* sgb = sigmas + (size_t)b * 2 * PLANE;
    const float sg0 = sgb[oy * IMG_W + ox];
    const float sg1 = sgb[PLANE + oy * IMG_W + ox];
    const float sig_s = 1.0f / (fabsf(sg0) + 1e-12f);
    const float sig_r = 1.0f / (fabsf(sg1) + 1e-12f);
    // w = exp2( sc * A + dsq * B ),  sc = ry^2 + rx^2,  dsq = sum_c (v_c - cen_c)^2
    const float A = -0.5f * 1.44269504f * sig_s * sig_s;
    const float B = -0.5f * 1.44269504f * sig_r * sig_r;

    const float4 cen = s_in[(ty + KR) * SPX + (tx + KR)];

    float wsum = 0.0f, acc0 = 0.0f, acc1 = 0.0f, acc2 = 0.0f;

    // Tap body: exact-zero arg at center (dsq computed by differences -> w==1 exact)
#define TAP(DX)                                                        \
    {                                                                  \
        const float rx2 = (float)((DX - KR) * (DX - KR));              \
        const float4 v = row[DX];                                      \
        const float d0 = v.x - cen.x;                                  \
        const float d1 = v.y - cen.y;                                  \
        const float d2 = v.z - cen.z;                                  \
        const float dsq = fmaf(d0, d0, fmaf(d1, d1, d2 * d2));         \
        const float scA = fmaf(rx2, A, syA);                           \
        const float w = __builtin_amdgcn_exp2f(fmaf(dsq, B, scA));     \
        wsum += w;                                                     \
        acc0 = fmaf(w, v.x, acc0);                                     \
        acc1 = fmaf(w, v.y, acc1);                                     \
        acc2 = fmaf(w, v.z, acc2);                                     \
    }

    if (tz == 0) {
        // dx 0..3 (36 taps)
        #pragma unroll 1
        for (int dy = 0; dy < KSZ; ++dy) {
            const float syA = (float)((dy - KR) * (dy - KR)) * A;
            const float4* __restrict__ row = &s_in[(ty + dy) * SPX + tx];
            TAP(0) TAP(1) TAP(2) TAP(3)
        }
    } else {
        // dx 4..8 (45 taps, includes center column)
        #pragma unroll 1
        for (int dy = 0; dy < KSZ; ++dy) {
            const float syA = (float)((dy - KR) * (dy - KR)) * A;
            const float4* __restrict__ row = &s_in[(ty + dy) * SPX + tx];
            TAP(4) TAP(5) TAP(6) TAP(7) TAP(8)
        }
    }
#undef TAP

    if (tz == 1)
        s_comb[ty * TILE_W + tx] = make_float4(wsum, acc0, acc1, acc2);
    __syncthreads();

    if (tz == 0) {
        const float4 o = s_comb[ty * TILE_W + tx];
        wsum += o.x; acc0 += o.y; acc1 += o.z; acc2 += o.w;
        const float inv = __builtin_amdgcn_rcpf(wsum);  // wsum >= 1 (center tap w == 1)
        float* outb = out + (size_t)b * 3 * PLANE;
        const int oidx = oy * IMG_W + ox;
        outb[oidx]             = acc0 * inv;
        outb[PLANE + oidx]     = acc1 * inv;
        outb[2 * PLANE + oidx] = acc2 * inv;
    }
}

extern "C" void kernel_launch(void* const* d_in, const int* in_sizes, int n_in,
                              void* d_out, int out_size, void* d_ws, size_t ws_size,
                              hipStream_t stream) {
    const float* input  = (const float*)d_in[0];
    const float* sigmas = (const float*)d_in[1];
    float* out = (float*)d_out;

    dim3 block(TILE_W, TILE_H, 2);
    dim3 grid(IMG_W / TILE_W, IMG_H / TILE_H, 2);  // 24 x 48 x 2 = 2304 blocks (9.0 / CU)
    abf_kernel<<<grid, block, 0, stream>>>(input, sigmas, out);
}

// Round 6
// 17.352 us; speedup vs baseline: 5.1698x; 1.0583x over previous
//
#include <hip/hip_runtime.h>
#include <hip/hip_bf16.h>

typedef float f32x2 __attribute__((ext_vector_type(2)));

#define IMG_H 384
#define IMG_W 384
#define KSZ 9
#define KR 4
#define TW 16                 // tile width (px) = 8 pixel-pairs
#define TH 8                  // tile height
#define NP (TW/2)             // 8 pairs per row
#define HW (TW + 2*KR)        // 24 halo width
#define HH (TH + 2*KR)        // 16 halo height
#define PST 48                // plane row stride (floats); 48 % 32 == 16 -> adjacent rows on disjoint bank halves
#define PLANE (IMG_H * IMG_W)

static __device__ __forceinline__ f32x2 mk2(float a, float b) { f32x2 r; r.x = a; r.y = b; return r; }

__global__ __launch_bounds__(192) void abf_kernel(
    const float* __restrict__ input,   // [2][3][384][384]
    const float* __restrict__ sigmas,  // [2][2][384][384]
    float* __restrict__ out)           // [2][3][384][384]
{
    __shared__ float s_in[3 * HH * PST];          // 3 channel planes, 9.2 KB
    __shared__ f32x2 s_comb[2][NP * TH][4];       // tz=1,2 partial sums, 4 KB

    const int b      = blockIdx.z;
    const int tile_x = blockIdx.x * TW;
    const int tile_y = blockIdx.y * TH;
    const int tx = threadIdx.x;  // 0..7  pair column
    const int ty = threadIdx.y;  // 0..7  row
    const int tz = threadIdx.z;  // 0..2  dy-group (wave-uniform: tid = tz*64 + ty*8 + tx)
    const int tid = (tz * TH + ty) * NP + tx;

    // ---- stage 24x16 halo, channel-planar ----
    const float* inb = input + (size_t)b * 3 * PLANE;
    for (int p = tid; p < 3 * HH * HW; p += 192) {
        int c   = p / (HH * HW);
        int rem = p - c * (HH * HW);
        int y   = rem / HW;
        int x   = rem - y * HW;
        int gy  = tile_y + y - KR;
        int gx  = tile_x + x - KR;
        float v = 0.f;
        if (gy >= 0 && gy < IMG_H && gx >= 0 && gx < IMG_W)
            v = inb[c * PLANE + gy * IMG_W + gx];
        s_in[(c * HH + y) * PST + x] = v;
    }
    __syncthreads();

    const int lx = 2 * tx;           // tile-local col of pixel A (pixel B = lx+1)
    const int ox = tile_x + lx;
    const int oy = tile_y + ty;

    const float* sgb = sigmas + (size_t)b * 2 * PLANE;
    const int sidx = oy * IMG_W + ox;
    const float sA0 = sgb[sidx],          sB0 = sgb[sidx + 1];
    const float sA1 = sgb[PLANE + sidx],  sB1 = sgb[PLANE + sidx + 1];
    const float isA = 1.f / (fabsf(sA0) + 1e-12f);
    const float isB = 1.f / (fabsf(sB0) + 1e-12f);
    const float irA = 1.f / (fabsf(sA1) + 1e-12f);
    const float irB = 1.f / (fabsf(sB1) + 1e-12f);
    // w = exp2(dsq*B + (rx2+ry2)*A), packed over the two pixels
    const f32x2 A = mk2(-0.72134752f * isA * isA, -0.72134752f * isB * isB);
    const f32x2 B = mk2(-0.72134752f * irA * irA, -0.72134752f * irB * irB);

    const int cb = (ty + KR) * PST + lx + KR;
    const f32x2 cen0 = mk2(s_in[0 * HH * PST + cb], s_in[0 * HH * PST + cb + 1]);
    const f32x2 cen1 = mk2(s_in[1 * HH * PST + cb], s_in[1 * HH * PST + cb + 1]);
    const f32x2 cen2 = mk2(s_in[2 * HH * PST + cb], s_in[2 * HH * PST + cb + 1]);

    f32x2 wsum = mk2(0.f, 0.f), a0 = wsum, a1 = wsum, a2 = wsum;

    // tz handles dy in {3tz, 3tz+1, 3tz+2} : perfect 3-way balance
    #pragma unroll 1
    for (int r = 0; r < 3; ++r) {
        const int dy = tz * 3 + r;
        const float ry2 = (float)((dy - KR) * (dy - KR));
        const f32x2 syA = ry2 * A;
        const int b0 = (0 * HH + ty + dy) * PST + lx;
        const int b1 = (1 * HH + ty + dy) * PST + lx;
        const int b2 = (2 * HH + ty + dy) * PST + lx;
        #pragma unroll
        for (int dx = 0; dx < KSZ; ++dx) {
            const float rx2 = (float)((dx - KR) * (dx - KR));
            const f32x2 v0 = mk2(s_in[b0 + dx], s_in[b0 + dx + 1]);
            const f32x2 v1 = mk2(s_in[b1 + dx], s_in[b1 + dx + 1]);
            const f32x2 v2 = mk2(s_in[b2 + dx], s_in[b2 + dx + 1]);
            const f32x2 d0 = v0 - cen0;
            const f32x2 d1 = v1 - cen1;
            const f32x2 d2 = v2 - cen2;
            const f32x2 dsq = d0 * d0 + d1 * d1 + d2 * d2;        // pk_fma chain
            const f32x2 arg = dsq * B + (rx2 * A + syA);          // 2x pk_fma
            const f32x2 w = mk2(__builtin_amdgcn_exp2f(arg.x),
                                __builtin_amdgcn_exp2f(arg.y));
            wsum += w;
            a0 += w * v0;
            a1 += w * v1;
            a2 += w * v2;
        }
    }

    const int pid = ty * NP + tx;
    if (tz > 0) {
        s_comb[tz - 1][pid][0] = wsum;
        s_comb[tz - 1][pid][1] = a0;
        s_comb[tz - 1][pid][2] = a1;
        s_comb[tz - 1][pid][3] = a2;
    }
    __syncthreads();

    if (tz == 0) {
        #pragma unroll
        for (int t = 0; t < 2; ++t) {
            wsum += s_comb[t][pid][0];
            a0   += s_comb[t][pid][1];
            a1   += s_comb[t][pid][2];
            a2   += s_comb[t][pid][3];
        }
        const f32x2 inv = mk2(__builtin_amdgcn_rcpf(wsum.x),
                              __builtin_amdgcn_rcpf(wsum.y));   // wsum >= 1 (center w == 1)
        float* outb = out + (size_t)b * 3 * PLANE;
        const int oidx = oy * IMG_W + ox;
        const f32x2 o0 = a0 * inv, o1 = a1 * inv, o2 = a2 * inv;
        *reinterpret_cast<float2*>(&outb[oidx])             = make_float2(o0.x, o0.y);
        *reinterpret_cast<float2*>(&outb[PLANE + oidx])     = make_float2(o1.x, o1.y);
        *reinterpret_cast<float2*>(&outb[2 * PLANE + oidx]) = make_float2(o2.x, o2.y);
    }
}

extern "C" void kernel_launch(void* const* d_in, const int* in_sizes, int n_in,
                              void* d_out, int out_size, void* d_ws, size_t ws_size,
                              hipStream_t stream) {
    const float* input  = (const float*)d_in[0];
    const float* sigmas = (const float*)d_in[1];
    float* out = (float*)d_out;

    dim3 block(NP, TH, 3);                          // (8,8,3) = 192 threads, 3 waves
    dim3 grid(IMG_W / TW, IMG_H / TH, 2);           // 24 x 48 x 2 = 2304 blocks (9/CU)
    abf_kernel<<<grid, block, 0, stream>>>(input, sigmas, out);
}

// Round 7
// 17.250 us; speedup vs baseline: 5.2004x; 1.0059x over previous
//
#include <hip/hip_runtime.h>
#include <hip/hip_bf16.h>

typedef float f32x2 __attribute__((ext_vector_type(2)));

#define IMG_H 384
#define IMG_W 384
#define KSZ 9
#define KR 4
#define TW 16                 // tile width (px) = 8 pixel-pairs
#define TH 8                  // tile height
#define NP (TW/2)             // 8 pairs per row
#define HW (TW + 2*KR)        // 24 halo width
#define HH (TH + 2*KR)        // 16 halo height
#define PST 36                // plane row stride (dwords); 36 % 32 == 4 -> 8 rows hit the 8
                              // distinct multiple-of-4 bank offsets => conflict-free floor
#define PLANE (IMG_H * IMG_W)

static __device__ __forceinline__ f32x2 mk2(float a, float b) { f32x2 r; r.x = a; r.y = b; return r; }

__global__ __launch_bounds__(192) void abf_kernel(
    const float* __restrict__ input,   // [2][3][384][384]
    const float* __restrict__ sigmas,  // [2][2][384][384]
    float* __restrict__ out)           // [2][3][384][384]
{
    __shared__ float s_in[3 * HH * PST];          // 6.75 KB, channel-planar
    __shared__ f32x2 s_comb[2][NP * TH][4];       // tz=1,2 partial sums, 4 KB

    const int b      = blockIdx.z;
    const int tile_x = blockIdx.x * TW;
    const int tile_y = blockIdx.y * TH;
    const int tx = threadIdx.x;  // 0..7  pair column
    const int ty = threadIdx.y;  // 0..7  row
    const int tz = threadIdx.z;  // 0..2  dy-group (wave-uniform)
    const int tid = (tz * TH + ty) * NP + tx;

    // ---- stage 24x16 halo, channel-planar, conflict-free stride ----
    const float* inb = input + (size_t)b * 3 * PLANE;
    for (int p = tid; p < 3 * HH * HW; p += 192) {
        int c   = p / (HH * HW);
        int rem = p - c * (HH * HW);
        int y   = rem / HW;
        int x   = rem - y * HW;
        int gy  = tile_y + y - KR;
        int gx  = tile_x + x - KR;
        float v = 0.f;
        if (gy >= 0 && gy < IMG_H && gx >= 0 && gx < IMG_W)
            v = inb[c * PLANE + gy * IMG_W + gx];
        s_in[(c * HH + y) * PST + x] = v;
    }
    __syncthreads();

    const int lx = 2 * tx;           // tile-local col of pixel A (pixel B = lx+1)
    const int ox = tile_x + lx;
    const int oy = tile_y + ty;

    const float* sgb = sigmas + (size_t)b * 2 * PLANE;
    const int sidx = oy * IMG_W + ox;
    const float sA0 = sgb[sidx],          sB0 = sgb[sidx + 1];
    const float sA1 = sgb[PLANE + sidx],  sB1 = sgb[PLANE + sidx + 1];
    const float isA = 1.f / (fabsf(sA0) + 1e-12f);
    const float isB = 1.f / (fabsf(sB0) + 1e-12f);
    const float irA = 1.f / (fabsf(sA1) + 1e-12f);
    const float irB = 1.f / (fabsf(sB1) + 1e-12f);
    // w = exp2(dsq*B + (rx2+ry2)*A), packed over the two pixels
    const f32x2 A = mk2(-0.72134752f * isA * isA, -0.72134752f * isB * isB);
    const f32x2 B = mk2(-0.72134752f * irA * irA, -0.72134752f * irB * irB);

    const int cb = (ty + KR) * PST + lx + KR;
    const f32x2 cen0 = mk2(s_in[0 * HH * PST + cb], s_in[0 * HH * PST + cb + 1]);
    const f32x2 cen1 = mk2(s_in[1 * HH * PST + cb], s_in[1 * HH * PST + cb + 1]);
    const f32x2 cen2 = mk2(s_in[2 * HH * PST + cb], s_in[2 * HH * PST + cb + 1]);

    f32x2 wsum = mk2(0.f, 0.f), a0 = wsum, a1 = wsum, a2 = wsum;

    // tz handles dy in {3tz, 3tz+1, 3tz+2} : perfect 3-way balance
    #pragma unroll 1
    for (int r = 0; r < 3; ++r) {
        const int dy = tz * 3 + r;
        const float ry2 = (float)((dy - KR) * (dy - KR));
        const f32x2 syA = ry2 * A;
        const int r0 = (0 * HH + ty + dy) * PST + lx;
        const int r1 = (1 * HH + ty + dy) * PST + lx;
        const int r2 = (2 * HH + ty + dy) * PST + lx;

        // register sliding window: 10 dwords per channel row, loaded once,
        // static indices only (adjacent pairs merge into ds_read2_b32)
        float w0[10], w1[10], w2[10];
        #pragma unroll
        for (int j = 0; j < 10; ++j) {
            w0[j] = s_in[r0 + j];
            w1[j] = s_in[r1 + j];
            w2[j] = s_in[r2 + j];
        }

        #pragma unroll
        for (int dx = 0; dx < KSZ; ++dx) {
            const float rx2 = (float)((dx - KR) * (dx - KR));
            const f32x2 v0 = mk2(w0[dx], w0[dx + 1]);
            const f32x2 v1 = mk2(w1[dx], w1[dx + 1]);
            const f32x2 v2 = mk2(w2[dx], w2[dx + 1]);
            const f32x2 d0 = v0 - cen0;
            const f32x2 d1 = v1 - cen1;
            const f32x2 d2 = v2 - cen2;
            const f32x2 dsq = d0 * d0 + d1 * d1 + d2 * d2;
            const f32x2 arg = dsq * B + (rx2 * A + syA);
            const f32x2 w = mk2(__builtin_amdgcn_exp2f(arg.x),
                                __builtin_amdgcn_exp2f(arg.y));
            wsum += w;
            a0 += w * v0;
            a1 += w * v1;
            a2 += w * v2;
        }
    }

    const int pid = ty * NP + tx;
    if (tz > 0) {
        s_comb[tz - 1][pid][0] = wsum;
        s_comb[tz - 1][pid][1] = a0;
        s_comb[tz - 1][pid][2] = a1;
        s_comb[tz - 1][pid][3] = a2;
    }
    __syncthreads();

    if (tz == 0) {
        #pragma unroll
        for (int t = 0; t < 2; ++t) {
            wsum += s_comb[t][pid][0];
            a0   += s_comb[t][pid][1];
            a1   += s_comb[t][pid][2];
            a2   += s_comb[t][pid][3];
        }
        const f32x2 inv = mk2(__builtin_amdgcn_rcpf(wsum.x),
                              __builtin_amdgcn_rcpf(wsum.y));   // wsum >= 1 (center w == 1)
        float* outb = out + (size_t)b * 3 * PLANE;
        const int oidx = oy * IMG_W + ox;
        const f32x2 o0 = a0 * inv, o1 = a1 * inv, o2 = a2 * inv;
        *reinterpret_cast<float2*>(&outb[oidx])             = make_float2(o0.x, o0.y);
        *reinterpret_cast<float2*>(&outb[PLANE + oidx])     = make_float2(o1.x, o1.y);
        *reinterpret_cast<float2*>(&outb[2 * PLANE + oidx]) = make_float2(o2.x, o2.y);
    }
}

extern "C" void kernel_launch(void* const* d_in, const int* in_sizes, int n_in,
                              void* d_out, int out_size, void* d_ws, size_t ws_size,
                              hipStream_t stream) {
    const float* input  = (const float*)d_in[0];
    const float* sigmas = (const float*)d_in[1];
    float* out = (float*)d_out;

    dim3 block(NP, TH, 3);                          // (8,8,3) = 192 threads, 3 waves
    dim3 grid(IMG_W / TW, IMG_H / TH, 2);           // 24 x 48 x 2 = 2304 blocks (9/CU)
    abf_kernel<<<grid, block, 0, stream>>>(input, sigmas, out);
}